// Round 6
// baseline (336.534 us; speedup 1.0000x reference)
//
#include <hip/hip_runtime.h>
#include <stdint.h>

// ---------------------------------------------------------------------------
// GCN 3-layer forward, MI355X. Round 6:
//  - k_mfma rewritten: global_load_lds(16B) staging, whole-K LDS panels
//    (BKT=128), 512 threads / 8 waves, 1-2 K-tiles -> 2 barriers per tile.
//    Both-sides XOR swizzle (seg ^= row&7) keeps ds_read_b128 conflict-free
//    while LDS dest stays lane-linear (global_load_lds constraint).
//  - agg kernels: MLP unroll 8.
// Pipeline unchanged:
//   CSR; ag=A_hat x (hi/lo); h1=relu(drop(ag@W1+b1)) (hi/lo); hw2=(h1@W2)*dinv;
//   h2=relu(drop(agg(hw2)+b2)) (hi/lo); out = h2@W3+b3.
// ---------------------------------------------------------------------------

typedef __attribute__((ext_vector_type(8))) short s8v;   // 8 bf16 (4 VGPR)
typedef __attribute__((ext_vector_type(4))) float f4v;   // 4 f32 acc

__device__ __host__ __forceinline__ uint32_t tf_rotl(uint32_t v, int r) {
  return (v << r) | (v >> (32 - r));
}

__device__ __host__ __forceinline__ void threefry2x32(uint32_t k0, uint32_t k1,
                                                      uint32_t x0, uint32_t x1,
                                                      uint32_t& o0, uint32_t& o1) {
  const uint32_t k2 = k0 ^ k1 ^ 0x1BD11BDAu;
  x0 += k0; x1 += k1;
#define TFR(r) { x0 += x1; x1 = tf_rotl(x1, r); x1 ^= x0; }
  TFR(13) TFR(15) TFR(26) TFR(6)
  x0 += k1; x1 += k2 + 1u;
  TFR(17) TFR(29) TFR(16) TFR(24)
  x0 += k2; x1 += k0 + 2u;
  TFR(13) TFR(15) TFR(26) TFR(6)
  x0 += k0; x1 += k1 + 3u;
  TFR(17) TFR(29) TFR(16) TFR(24)
  x0 += k1; x1 += k2 + 4u;
  TFR(13) TFR(15) TFR(26) TFR(6)
  x0 += k2; x1 += k0 + 5u;
#undef TFR
  o0 = x0; o1 = x1;
}

__device__ __forceinline__ bool drop_keep(uint32_t k0, uint32_t k1, uint32_t j) {
  uint32_t a, b;
  threefry2x32(k0, k1, 0u, j, a, b);
  uint32_t bits = a ^ b;
  float u = __uint_as_float((bits >> 9) | 0x3f800000u) - 1.0f;
  return u < 0.8f;
}

__device__ __forceinline__ uint16_t f2bf(float f) {
  uint32_t u = __float_as_uint(f);
  return (uint16_t)((u + 0x7FFFu + ((u >> 16) & 1u)) >> 16);
}
__device__ __forceinline__ float bf2f(uint16_t h) {
  return __uint_as_float((uint32_t)h << 16);
}

// async global->LDS, 16B per lane; lds ptr must be wave-uniform (HW adds lane*16)
__device__ __forceinline__ void gll16(const void* g, void* l) {
  __builtin_amdgcn_global_load_lds(
      (const __attribute__((address_space(1))) uint32_t*)g,
      (__attribute__((address_space(3))) uint32_t*)l, 16, 0, 0);
}

// ------------------------- CSR build -------------------------
__global__ void k_hist(const int* __restrict__ tgt, int* __restrict__ cnt, int E) {
  int e = blockIdx.x * 256 + threadIdx.x;
  if (e < E) atomicAdd(&cnt[tgt[e]], 1);
}

__global__ __launch_bounds__(256) void k_scan1(const int* __restrict__ cnt,
                                               int* __restrict__ row_start,
                                               int* __restrict__ bsum,
                                               float* __restrict__ dinv, int n) {
  int tid = threadIdx.x;
  int i = blockIdx.x * 256 + tid;
  int c = (i < n) ? cnt[i] : 0;
  if (i < n) dinv[i] = rsqrtf((float)(c + 1));  // +1 self-loop
  int lane = tid & 63, wv = tid >> 6;
  int v = c;
#pragma unroll
  for (int d = 1; d < 64; d <<= 1) {
    int u = __shfl_up(v, d);
    if (lane >= d) v += u;
  }
  __shared__ int ws[4];
  if (lane == 63) ws[wv] = v;
  __syncthreads();
  int add = 0;
#pragma unroll
  for (int w = 0; w < 4; ++w)
    if (w < wv) add += ws[w];
  int incl = v + add;
  if (i < n) row_start[i] = incl - c;
  if (tid == 255) bsum[blockIdx.x] = incl;
}

__global__ __launch_bounds__(256) void k_scan2(const int* __restrict__ bsum,
                                               int* __restrict__ bbase,
                                               int* __restrict__ row_start,
                                               int nb, int n) {
  int tid = threadIdx.x;
  int c = (tid < nb) ? bsum[tid] : 0;
  int lane = tid & 63, wv = tid >> 6;
  int v = c;
#pragma unroll
  for (int d = 1; d < 64; d <<= 1) {
    int u = __shfl_up(v, d);
    if (lane >= d) v += u;
  }
  __shared__ int ws[4];
  if (lane == 63) ws[wv] = v;
  __syncthreads();
  int add = 0;
#pragma unroll
  for (int w = 0; w < 4; ++w)
    if (w < wv) add += ws[w];
  int incl = v + add;
  if (tid < nb) bbase[tid] = incl - c;
  if (tid == 255) row_start[n] = incl;
}

__global__ void k_scan3(int* __restrict__ row_start, const int* __restrict__ bbase, int n) {
  int i = blockIdx.x * 256 + threadIdx.x;
  if (i < n) row_start[i] += bbase[blockIdx.x];
}

__global__ void k_scatter(const int* __restrict__ src, const int* __restrict__ tgt,
                          const int* __restrict__ row_start, int* __restrict__ cursor,
                          int* __restrict__ csr_src, int E) {
  int e = blockIdx.x * 256 + threadIdx.x;
  if (e >= E) return;
  int t = tgt[e];
  int pos = atomicAdd(&cursor[t], 1);
  csr_src[row_start[t] + pos] = src[e];
}

// ------------------------- weight transpose + hi/lo split -------------------------
__global__ void k_cvtW(const float* __restrict__ W, uint16_t* __restrict__ Wth,
                       uint16_t* __restrict__ Wtl, int K, int N) {
  int i = blockIdx.x * 256 + threadIdx.x;
  if (i >= N * K) return;
  int nn = i / K, kk = i - nn * K;
  float v = W[(size_t)kk * N + nn];
  uint16_t h = f2bf(v);
  Wth[i] = h;
  Wtl[i] = f2bf(v - bf2f(h));
}

// ------------------------- split-bf16 MFMA GEMM (gload_lds, whole-K panels) -------
// BM=128, BKT=128 (K-tile), BN template (128 or 64). 512 thr = 8 waves (2x4).
// LDS: lAh/lAl [128][128], lBh/lBl [BN][128]; seg-XOR swizzle (seg ^ row&7).
// MODE 0: Cf = acc*sb[row];  MODE 1: Cf = acc+sb[col];  MODE 2: hi/lo(relu(drop(acc+sb[col])))
template <int BN, int MODE>
__global__ __launch_bounds__(512) void k_mfma(
    const uint16_t* __restrict__ Ah, const uint16_t* __restrict__ Al,
    const uint16_t* __restrict__ Bh, const uint16_t* __restrict__ Bl,
    const float* __restrict__ sb, float* __restrict__ Cf,
    uint16_t* __restrict__ Chi, uint16_t* __restrict__ Clo,
    int M, int N, int K, uint32_t k0, uint32_t k1) {
  const int BKT = 128;
  const int NREP = BN / 64;  // col-blocks of 16 per wave
  extern __shared__ uint16_t smem[];
  uint16_t* lAh = smem;                  // [128][128]
  uint16_t* lAl = lAh + 128 * BKT;
  uint16_t* lBh = lAl + 128 * BKT;       // [BN][128]
  uint16_t* lBl = lBh + BN * BKT;

  int tid = threadIdx.x;
  int lane = tid & 63;
  int wid = tid >> 6;
  int wm = wid & 1, wn = wid >> 1;       // 2 x 4 wave grid
  int bm = blockIdx.x * 128, bn = blockIdx.y * BN;

  f4v acc[4][NREP] = {};
  int NKT = K / BKT;

  for (int kt = 0; kt < NKT; ++kt) {
    if (kt) __syncthreads();  // protect LDS reuse
    int kk = kt * BKT;
    // ---- stage A hi/lo: 2048 chunks of 16B, 4 per thread ----
#pragma unroll
    for (int p = 0; p < 4; ++p) {
      int c = p * 512 + tid;
      int row = c >> 4, u = c & 15;
      int seg = u ^ (row & 7);           // inverse-swizzled global source
      size_t go = (size_t)(bm + row) * K + kk + seg * 8;
      int cbase = p * 512 + (wid << 6);  // wave-uniform LDS chunk base
      gll16(Ah + go, lAh + (size_t)cbase * 8);
      gll16(Al + go, lAl + (size_t)cbase * 8);
    }
    // ---- stage B hi/lo: BN*16 chunks ----
#pragma unroll
    for (int p = 0; p < BN / 32; ++p) {
      int c = p * 512 + tid;
      int row = c >> 4, u = c & 15;
      int seg = u ^ (row & 7);
      size_t go = (size_t)(bn + row) * K + kk + seg * 8;
      int cbase = p * 512 + (wid << 6);
      gll16(Bh + go, lBh + (size_t)cbase * 8);
      gll16(Bl + go, lBl + (size_t)cbase * 8);
    }
    asm volatile("s_waitcnt vmcnt(0)" ::: "memory");
    __syncthreads();

    // ---- compute: 4 k-steps of 32 ----
    int r16 = lane & 15, kq = lane >> 4;
#pragma unroll
    for (int ks = 0; ks < 4; ++ks) {
      s8v ah[4], al[4], bh[NREP], bl[NREP];
#pragma unroll
      for (int mb = 0; mb < 4; ++mb) {
        int row = wm * 64 + mb * 16 + r16;
        int u = (ks * 4 + kq) ^ (row & 7);  // swizzled read
        ah[mb] = *(const s8v*)&lAh[(size_t)row * BKT + u * 8];
        al[mb] = *(const s8v*)&lAl[(size_t)row * BKT + u * 8];
      }
#pragma unroll
      for (int nb = 0; nb < NREP; ++nb) {
        int row = wn * (NREP * 16) + nb * 16 + r16;
        int u = (ks * 4 + kq) ^ (row & 7);
        bh[nb] = *(const s8v*)&lBh[(size_t)row * BKT + u * 8];
        bl[nb] = *(const s8v*)&lBl[(size_t)row * BKT + u * 8];
      }
#pragma unroll
      for (int mb = 0; mb < 4; ++mb)
#pragma unroll
        for (int nb = 0; nb < NREP; ++nb) {
          acc[mb][nb] = __builtin_amdgcn_mfma_f32_16x16x32_bf16(ah[mb], bh[nb], acc[mb][nb], 0, 0, 0);
          acc[mb][nb] = __builtin_amdgcn_mfma_f32_16x16x32_bf16(ah[mb], bl[nb], acc[mb][nb], 0, 0, 0);
          acc[mb][nb] = __builtin_amdgcn_mfma_f32_16x16x32_bf16(al[mb], bh[nb], acc[mb][nb], 0, 0, 0);
        }
    }
  }

  // ---- epilogue ----
#pragma unroll
  for (int mb = 0; mb < 4; ++mb) {
#pragma unroll
    for (int nb = 0; nb < NREP; ++nb) {
#pragma unroll
      for (int r = 0; r < 4; ++r) {
        int row = bm + wm * 64 + mb * 16 + (lane >> 4) * 4 + r;
        int col = bn + wn * (NREP * 16) + nb * 16 + (lane & 15);
        if (row >= M) continue;
        float v = acc[mb][nb][r];
        size_t o = (size_t)row * N + col;
        if (MODE == 0) {
          Cf[o] = v * sb[row];
        } else if (MODE == 1) {
          Cf[o] = v + sb[col];
        } else {
          v += sb[col];
          uint32_t j = (uint32_t)row * (uint32_t)N + (uint32_t)col;
          v = drop_keep(k0, k1, j) ? fmaxf(v * 1.25f, 0.f) : 0.f;
          uint16_t h = f2bf(v);
          Chi[o] = h;
          Clo[o] = f2bf(v - bf2f(h));
        }
      }
    }
  }
}

// ------------------------- layer-1 aggregation -> bf16 hi/lo (MLP-8) --------------
__global__ __launch_bounds__(256) void k_agg_x(const float* __restrict__ x,
                                               const float* __restrict__ dinv,
                                               const int* __restrict__ row_start,
                                               const int* __restrict__ csr_src,
                                               uint32_t* __restrict__ outh,
                                               uint32_t* __restrict__ outl, int n) {
  const int F = 128;
  int wid = (int)((blockIdx.x * 256 + threadIdx.x) >> 6);
  if (wid >= n) return;
  int lane = threadIdx.x & 63;
  int t = wid;
  float dt = dinv[t];
  float2 xt = ((const float2*)(x + (size_t)t * F))[lane];
  float2 a[8];
  a[0] = make_float2(xt.x * dt, xt.y * dt);
#pragma unroll
  for (int q = 1; q < 8; ++q) a[q] = make_float2(0.f, 0.f);
  int e0 = row_start[t], e1 = row_start[t + 1];
  int e = e0;
  for (; e + 8 <= e1; e += 8) {
#pragma unroll
    for (int q = 0; q < 8; ++q) {
      int s = csr_src[e + q];
      float ds = dinv[s];
      float2 v = ((const float2*)(x + (size_t)s * F))[lane];
      a[q].x += v.x * ds;
      a[q].y += v.y * ds;
    }
  }
  for (; e < e1; ++e) {
    int s = csr_src[e];
    float ds = dinv[s];
    float2 v = ((const float2*)(x + (size_t)s * F))[lane];
    a[0].x += v.x * ds; a[0].y += v.y * ds;
  }
  float rx = (((a[0].x + a[1].x) + (a[2].x + a[3].x)) + ((a[4].x + a[5].x) + (a[6].x + a[7].x))) * dt;
  float ry = (((a[0].y + a[1].y) + (a[2].y + a[3].y)) + ((a[4].y + a[5].y) + (a[6].y + a[7].y))) * dt;
  uint16_t hx = f2bf(rx), hy = f2bf(ry);
  uint16_t lx = f2bf(rx - bf2f(hx)), ly = f2bf(ry - bf2f(hy));
  outh[(size_t)t * 64 + lane] = (uint32_t)hx | ((uint32_t)hy << 16);
  outl[(size_t)t * 64 + lane] = (uint32_t)lx | ((uint32_t)ly << 16);
}

// ------------------------- layer-2 aggregation + bias + drop + relu (MLP-8) -------
__global__ __launch_bounds__(256) void k_agg_w(const float* __restrict__ hws,
                                               const float* __restrict__ dinv,
                                               const float* __restrict__ bias,
                                               const int* __restrict__ row_start,
                                               const int* __restrict__ csr_src,
                                               uint32_t* __restrict__ outh,
                                               uint32_t* __restrict__ outl,
                                               uint32_t k0, uint32_t k1, int n) {
  const int F = 128;
  int wid = (int)((blockIdx.x * 256 + threadIdx.x) >> 6);
  if (wid >= n) return;
  int lane = threadIdx.x & 63;
  int t = wid;
  float2 a[8];
  a[0] = ((const float2*)(hws + (size_t)t * F))[lane];
#pragma unroll
  for (int q = 1; q < 8; ++q) a[q] = make_float2(0.f, 0.f);
  int e0 = row_start[t], e1 = row_start[t + 1];
  int e = e0;
  for (; e + 8 <= e1; e += 8) {
#pragma unroll
    for (int q = 0; q < 8; ++q) {
      int s = csr_src[e + q];
      float2 v = ((const float2*)(hws + (size_t)s * F))[lane];
      a[q].x += v.x;
      a[q].y += v.y;
    }
  }
  for (; e < e1; ++e) {
    int s = csr_src[e];
    float2 v = ((const float2*)(hws + (size_t)s * F))[lane];
    a[0].x += v.x; a[0].y += v.y;
  }
  float d = dinv[t];
  float sx = ((a[0].x + a[1].x) + (a[2].x + a[3].x)) + ((a[4].x + a[5].x) + (a[6].x + a[7].x));
  float sy = ((a[0].y + a[1].y) + (a[2].y + a[3].y)) + ((a[4].y + a[5].y) + (a[6].y + a[7].y));
  float vx = sx * d + bias[lane * 2];
  float vy = sy * d + bias[lane * 2 + 1];
  uint32_t j = (uint32_t)t * 128u + (uint32_t)lane * 2u;
  vx = drop_keep(k0, k1, j)     ? fmaxf(vx * 1.25f, 0.f) : 0.f;
  vy = drop_keep(k0, k1, j + 1) ? fmaxf(vy * 1.25f, 0.f) : 0.f;
  uint16_t hx = f2bf(vx), hy = f2bf(vy);
  uint16_t lx = f2bf(vx - bf2f(hx)), ly = f2bf(vy - bf2f(hy));
  outh[(size_t)t * 64 + lane] = (uint32_t)hx | ((uint32_t)hy << 16);
  outl[(size_t)t * 64 + lane] = (uint32_t)lx | ((uint32_t)ly << 16);
}

// ------------------------- launch -------------------------
static inline size_t ws_align(size_t x) { return (x + 255) & ~(size_t)255; }

extern "C" void kernel_launch(void* const* d_in, const int* in_sizes, int n_in,
                              void* d_out, int out_size, void* d_ws, size_t ws_size,
                              hipStream_t stream) {
  const float* x  = (const float*)d_in[0];
  const float* W1 = (const float*)d_in[1];
  const float* b1 = (const float*)d_in[2];
  const float* W2 = (const float*)d_in[3];
  const float* b2 = (const float*)d_in[4];
  const float* W3 = (const float*)d_in[5];
  const float* b3 = (const float*)d_in[6];
  const int*   ei = (const int*)d_in[7];

  const int IN = 128, H2 = 256, HID = 128, OD = 64;
  const int n = in_sizes[0] / IN;   // 50000
  const int E = in_sizes[7] / 2;    // 800000
  const int* esrc = ei;
  const int* etgt = ei + E;
  const int nb = (n + 255) / 256;
  const int Mb = (n + 127) / 128;   // 391
  const int Mpad = Mb * 128;        // 50048

  char* w = (char*)d_ws;
  size_t off = 0;
  auto alloc = [&](size_t bytes) { void* p = w + off; off += ws_align(bytes); return p; };
  float*    dinv      = (float*)alloc((size_t)n * 4);
  int*      cnt       = (int*)alloc((size_t)n * 4);
  int*      cursor    = (int*)alloc((size_t)n * 4);
  int*      row_start = (int*)alloc(((size_t)n + 1) * 4);
  int*      bsum      = (int*)alloc(256 * 4);
  int*      bbase     = (int*)alloc(256 * 4);
  int*      csr_src   = (int*)alloc((size_t)E * 4);
  uint16_t* A1h       = (uint16_t*)alloc((size_t)Mpad * IN * 2);   // also h2 (aliased)
  uint16_t* A1l       = (uint16_t*)alloc((size_t)Mpad * IN * 2);
  uint16_t* h1h       = (uint16_t*)alloc((size_t)Mpad * H2 * 2);
  uint16_t* h1l       = (uint16_t*)alloc((size_t)Mpad * H2 * 2);
  float*    hw2       = (float*)alloc((size_t)n * HID * 4);
  uint16_t* Wt1h      = (uint16_t*)alloc((size_t)H2 * IN * 2);
  uint16_t* Wt1l      = (uint16_t*)alloc((size_t)H2 * IN * 2);
  uint16_t* Wt2h      = (uint16_t*)alloc((size_t)HID * H2 * 2);
  uint16_t* Wt2l      = (uint16_t*)alloc((size_t)HID * H2 * 2);
  uint16_t* Wt3h      = (uint16_t*)alloc((size_t)OD * IN * 2);
  uint16_t* Wt3l      = (uint16_t*)alloc((size_t)OD * IN * 2);
  (void)ws_size;

  // allow 128KB dynamic LDS (idempotent host-side attribute set)
  hipFuncSetAttribute((const void*)&k_mfma<128, 2>,
                      hipFuncAttributeMaxDynamicSharedMemorySize, 131072);
  hipFuncSetAttribute((const void*)&k_mfma<128, 0>,
                      hipFuncAttributeMaxDynamicSharedMemorySize, 131072);
  hipFuncSetAttribute((const void*)&k_mfma<64, 1>,
                      hipFuncAttributeMaxDynamicSharedMemorySize, 98304);

  uint32_t dk1_0, dk1_1, dk2_0, dk2_1;
  threefry2x32(0u, 42u, 0u, 0u, dk1_0, dk1_1);
  threefry2x32(0u, 42u, 0u, 1u, dk2_0, dk2_1);

  int padrows = Mpad - n;
  hipMemsetAsync(A1h + (size_t)n * IN, 0, (size_t)padrows * IN * 2, stream);
  hipMemsetAsync(A1l + (size_t)n * IN, 0, (size_t)padrows * IN * 2, stream);
  hipMemsetAsync(h1h + (size_t)n * H2, 0, (size_t)padrows * H2 * 2, stream);
  hipMemsetAsync(h1l + (size_t)n * H2, 0, (size_t)padrows * H2 * 2, stream);
  hipMemsetAsync(cnt, 0, (size_t)n * 4, stream);
  hipMemsetAsync(cursor, 0, (size_t)n * 4, stream);

  k_cvtW<<<(H2 * IN + 255) / 256, 256, 0, stream>>>(W1, Wt1h, Wt1l, IN, H2);
  k_cvtW<<<(HID * H2 + 255) / 256, 256, 0, stream>>>(W2, Wt2h, Wt2l, H2, HID);
  k_cvtW<<<(OD * IN + 255) / 256, 256, 0, stream>>>(W3, Wt3h, Wt3l, IN, OD);

  k_hist<<<(E + 255) / 256, 256, 0, stream>>>(etgt, cnt, E);
  k_scan1<<<nb, 256, 0, stream>>>(cnt, row_start, bsum, dinv, n);
  k_scan2<<<1, 256, 0, stream>>>(bsum, bbase, row_start, nb, n);
  k_scan3<<<nb, 256, 0, stream>>>(row_start, bbase, n);
  k_scatter<<<(E + 255) / 256, 256, 0, stream>>>(esrc, etgt, row_start, cursor, csr_src, E);

  // layer 1
  k_agg_x<<<(n + 3) / 4, 256, 0, stream>>>(x, dinv, row_start, csr_src,
                                           (uint32_t*)A1h, (uint32_t*)A1l, n);
  {
    dim3 g(Mb, H2 / 128);
    k_mfma<128, 2><<<g, 512, 131072, stream>>>(A1h, A1l, Wt1h, Wt1l, b1, nullptr,
                                               h1h, h1l, n, H2, IN, dk1_0, dk1_1);
  }

  // layer 2
  {
    dim3 g(Mb, 1);
    k_mfma<128, 0><<<g, 512, 131072, stream>>>(h1h, h1l, Wt2h, Wt2l, dinv, hw2,
                                               nullptr, nullptr, n, HID, H2, 0u, 0u);
  }
  k_agg_w<<<(n + 3) / 4, 256, 0, stream>>>(hw2, dinv, b2, row_start, csr_src,
                                           (uint32_t*)A1h, (uint32_t*)A1l, dk2_0, dk2_1, n);

  // layer 3
  {
    dim3 g(Mb, 1);
    k_mfma<64, 1><<<g, 512, 98304, stream>>>(A1h, A1l, Wt3h, Wt3l, b3, (float*)d_out,
                                             nullptr, nullptr, n, OD, IN, 0u, 0u);
  }
}

// Round 7
// 292.687 us; speedup vs baseline: 1.1498x; 1.1498x over previous
//
#include <hip/hip_runtime.h>
#include <hip/hip_fp16.h>
#include <stdint.h>

// ---------------------------------------------------------------------------
// GCN 3-layer forward, MI355X. Round 7:
//  - k_mfma: BM=64/BN=64/BKT=128, 256 thr, 64KB LDS -> 2 blocks/CU, 4x blocks
//    (cross-block stage/compute overlap; r6's 128KB 1-block/CU serialized).
//  - aggs gather f16 (half the bytes): xs16 = f16(x*dinv) precomputed;
//    layer-2 GEMM writes hw2 as f16.
// Pipeline:
//   CSR; xs16=f16(x*dinv); ag=dt*sum xs16 (hi/lo bf16);
//   h1=relu(drop(ag@W1+b1)) (hi/lo); hw2_16=f16((h1@W2)*dinv);
//   h2=relu(drop(dt*sum hw2_16 + b2)) (hi/lo); out=h2@W3+b3 (fp32).
// ---------------------------------------------------------------------------

typedef __attribute__((ext_vector_type(8))) short s8v;   // 8 bf16 (4 VGPR)
typedef __attribute__((ext_vector_type(4))) float f4v;   // 4 f32 acc

__device__ __host__ __forceinline__ uint32_t tf_rotl(uint32_t v, int r) {
  return (v << r) | (v >> (32 - r));
}

__device__ __host__ __forceinline__ void threefry2x32(uint32_t k0, uint32_t k1,
                                                      uint32_t x0, uint32_t x1,
                                                      uint32_t& o0, uint32_t& o1) {
  const uint32_t k2 = k0 ^ k1 ^ 0x1BD11BDAu;
  x0 += k0; x1 += k1;
#define TFR(r) { x0 += x1; x1 = tf_rotl(x1, r); x1 ^= x0; }
  TFR(13) TFR(15) TFR(26) TFR(6)
  x0 += k1; x1 += k2 + 1u;
  TFR(17) TFR(29) TFR(16) TFR(24)
  x0 += k2; x1 += k0 + 2u;
  TFR(13) TFR(15) TFR(26) TFR(6)
  x0 += k0; x1 += k1 + 3u;
  TFR(17) TFR(29) TFR(16) TFR(24)
  x0 += k1; x1 += k2 + 4u;
  TFR(13) TFR(15) TFR(26) TFR(6)
  x0 += k2; x1 += k0 + 5u;
#undef TFR
  o0 = x0; o1 = x1;
}

__device__ __forceinline__ bool drop_keep(uint32_t k0, uint32_t k1, uint32_t j) {
  uint32_t a, b;
  threefry2x32(k0, k1, 0u, j, a, b);
  uint32_t bits = a ^ b;
  float u = __uint_as_float((bits >> 9) | 0x3f800000u) - 1.0f;
  return u < 0.8f;
}

__device__ __forceinline__ uint16_t f2bf(float f) {
  uint32_t u = __float_as_uint(f);
  return (uint16_t)((u + 0x7FFFu + ((u >> 16) & 1u)) >> 16);
}
__device__ __forceinline__ float bf2f(uint16_t h) {
  return __uint_as_float((uint32_t)h << 16);
}

// async global->LDS, 16B/lane; lds base wave-uniform (HW adds lane*16)
__device__ __forceinline__ void gll16(const void* g, void* l) {
  __builtin_amdgcn_global_load_lds(
      (const __attribute__((address_space(1))) uint32_t*)g,
      (__attribute__((address_space(3))) uint32_t*)l, 16, 0, 0);
}

// ------------------------- CSR build -------------------------
__global__ void k_hist(const int* __restrict__ tgt, int* __restrict__ cnt, int E) {
  int e = blockIdx.x * 256 + threadIdx.x;
  if (e < E) atomicAdd(&cnt[tgt[e]], 1);
}

__global__ __launch_bounds__(256) void k_scan1(const int* __restrict__ cnt,
                                               int* __restrict__ row_start,
                                               int* __restrict__ bsum,
                                               float* __restrict__ dinv, int n) {
  int tid = threadIdx.x;
  int i = blockIdx.x * 256 + tid;
  int c = (i < n) ? cnt[i] : 0;
  if (i < n) dinv[i] = rsqrtf((float)(c + 1));  // +1 self-loop
  int lane = tid & 63, wv = tid >> 6;
  int v = c;
#pragma unroll
  for (int d = 1; d < 64; d <<= 1) {
    int u = __shfl_up(v, d);
    if (lane >= d) v += u;
  }
  __shared__ int ws[4];
  if (lane == 63) ws[wv] = v;
  __syncthreads();
  int add = 0;
#pragma unroll
  for (int w = 0; w < 4; ++w)
    if (w < wv) add += ws[w];
  int incl = v + add;
  if (i < n) row_start[i] = incl - c;
  if (tid == 255) bsum[blockIdx.x] = incl;
}

__global__ __launch_bounds__(256) void k_scan2(const int* __restrict__ bsum,
                                               int* __restrict__ bbase,
                                               int* __restrict__ row_start,
                                               int nb, int n) {
  int tid = threadIdx.x;
  int c = (tid < nb) ? bsum[tid] : 0;
  int lane = tid & 63, wv = tid >> 6;
  int v = c;
#pragma unroll
  for (int d = 1; d < 64; d <<= 1) {
    int u = __shfl_up(v, d);
    if (lane >= d) v += u;
  }
  __shared__ int ws[4];
  if (lane == 63) ws[wv] = v;
  __syncthreads();
  int add = 0;
#pragma unroll
  for (int w = 0; w < 4; ++w)
    if (w < wv) add += ws[w];
  int incl = v + add;
  if (tid < nb) bbase[tid] = incl - c;
  if (tid == 255) row_start[n] = incl;
}

__global__ void k_scan3(int* __restrict__ row_start, const int* __restrict__ bbase, int n) {
  int i = blockIdx.x * 256 + threadIdx.x;
  if (i < n) row_start[i] += bbase[blockIdx.x];
}

__global__ void k_scatter(const int* __restrict__ src, const int* __restrict__ tgt,
                          const int* __restrict__ row_start, int* __restrict__ cursor,
                          int* __restrict__ csr_src, int E) {
  int e = blockIdx.x * 256 + threadIdx.x;
  if (e >= E) return;
  int t = tgt[e];
  int pos = atomicAdd(&cursor[t], 1);
  csr_src[row_start[t] + pos] = src[e];
}

// ------------------------- weight transpose + hi/lo split -------------------------
__global__ void k_cvtW(const float* __restrict__ W, uint16_t* __restrict__ Wth,
                       uint16_t* __restrict__ Wtl, int K, int N) {
  int i = blockIdx.x * 256 + threadIdx.x;
  if (i >= N * K) return;
  int nn = i / K, kk = i - nn * K;
  float v = W[(size_t)kk * N + nn];
  uint16_t h = f2bf(v);
  Wth[i] = h;
  Wtl[i] = f2bf(v - bf2f(h));
}

// ------------------------- xs16 = f16(x * dinv[row]) -------------------------
__global__ void k_scale16(const float* __restrict__ x, const float* __restrict__ dinv,
                          uint16_t* __restrict__ xs, int total2) {
  int i = blockIdx.x * 256 + threadIdx.x;
  if (i >= total2) return;
  float2 v = ((const float2*)x)[i];
  float s = dinv[i >> 6];  // 64 float2 per 128-float row
  __half2 h;
  h.x = __float2half_rn(v.x * s);
  h.y = __float2half_rn(v.y * s);
  ((__half2*)xs)[i] = h;
}

// ------------------------- split-bf16 MFMA GEMM (64x64 tiles, gload_lds) ----------
// BM=64, BN=64, BKT=128; 256 thr / 4 waves (2x2), wave tile 32x32.
// LDS 64 KB -> 2 blocks/CU. seg^(row&7) both-sides swizzle.
// MODE 0: Chi[o] = f16(acc*sb[row])   (hw2, f16 out)
// MODE 1: Cf[o]  = acc + sb[col]      (final output, fp32)
// MODE 2: Chi/Clo = bf16 hi/lo of relu(drop(acc+sb[col]))
template <int MODE>
__global__ __launch_bounds__(256) void k_mfma(
    const uint16_t* __restrict__ Ah, const uint16_t* __restrict__ Al,
    const uint16_t* __restrict__ Bh, const uint16_t* __restrict__ Bl,
    const float* __restrict__ sb, float* __restrict__ Cf,
    uint16_t* __restrict__ Chi, uint16_t* __restrict__ Clo,
    int M, int N, int K, uint32_t k0, uint32_t k1) {
  const int BKT = 128;
  extern __shared__ uint16_t smem[];
  uint16_t* lAh = smem;              // [64][128]
  uint16_t* lAl = lAh + 64 * BKT;
  uint16_t* lBh = lAl + 64 * BKT;
  uint16_t* lBl = lBh + 64 * BKT;

  int tid = threadIdx.x;
  int lane = tid & 63;
  int wid = tid >> 6;
  int wm = wid & 1, wn = wid >> 1;   // 2x2 wave grid
  int bm = blockIdx.x * 64, bn = blockIdx.y * 64;

  f4v acc[2][2] = {};
  int NKT = K / BKT;

  for (int kt = 0; kt < NKT; ++kt) {
    if (kt) __syncthreads();
    int kk = kt * BKT;
    // stage A,B hi/lo: 64 rows x 16 chunks each
#pragma unroll
    for (int p = 0; p < 4; ++p) {
      int c = p * 256 + tid;
      int row = c >> 4, u = c & 15;
      int seg = u ^ (row & 7);       // inverse-swizzled global source
      int cbase = p * 256 + (wid << 6);
      size_t ga = (size_t)(bm + row) * K + kk + seg * 8;
      gll16(Ah + ga, lAh + (size_t)cbase * 8);
      gll16(Al + ga, lAl + (size_t)cbase * 8);
      size_t gb = (size_t)(bn + row) * K + kk + seg * 8;
      gll16(Bh + gb, lBh + (size_t)cbase * 8);
      gll16(Bl + gb, lBl + (size_t)cbase * 8);
    }
    asm volatile("s_waitcnt vmcnt(0)" ::: "memory");
    __syncthreads();

    int r16 = lane & 15, kq = lane >> 4;
#pragma unroll
    for (int ks = 0; ks < 4; ++ks) {
      s8v ah[2], al[2], bh[2], bl[2];
#pragma unroll
      for (int mb = 0; mb < 2; ++mb) {
        int row = wm * 32 + mb * 16 + r16;
        int u = (ks * 4 + kq) ^ (row & 7);
        ah[mb] = *(const s8v*)&lAh[(size_t)row * BKT + u * 8];
        al[mb] = *(const s8v*)&lAl[(size_t)row * BKT + u * 8];
      }
#pragma unroll
      for (int nb = 0; nb < 2; ++nb) {
        int row = wn * 32 + nb * 16 + r16;
        int u = (ks * 4 + kq) ^ (row & 7);
        bh[nb] = *(const s8v*)&lBh[(size_t)row * BKT + u * 8];
        bl[nb] = *(const s8v*)&lBl[(size_t)row * BKT + u * 8];
      }
#pragma unroll
      for (int mb = 0; mb < 2; ++mb)
#pragma unroll
        for (int nb = 0; nb < 2; ++nb) {
          acc[mb][nb] = __builtin_amdgcn_mfma_f32_16x16x32_bf16(ah[mb], bh[nb], acc[mb][nb], 0, 0, 0);
          acc[mb][nb] = __builtin_amdgcn_mfma_f32_16x16x32_bf16(ah[mb], bl[nb], acc[mb][nb], 0, 0, 0);
          acc[mb][nb] = __builtin_amdgcn_mfma_f32_16x16x32_bf16(al[mb], bh[nb], acc[mb][nb], 0, 0, 0);
        }
    }
  }

  // epilogue
#pragma unroll
  for (int mb = 0; mb < 2; ++mb) {
#pragma unroll
    for (int nb = 0; nb < 2; ++nb) {
#pragma unroll
      for (int r = 0; r < 4; ++r) {
        int row = bm + wm * 32 + mb * 16 + (lane >> 4) * 4 + r;
        int col = bn + wn * 32 + nb * 16 + (lane & 15);
        if (row >= M) continue;
        float v = acc[mb][nb][r];
        size_t o = (size_t)row * N + col;
        if (MODE == 0) {
          Chi[o] = __half_as_ushort(__float2half_rn(v * sb[row]));
        } else if (MODE == 1) {
          Cf[o] = v + sb[col];
        } else {
          v += sb[col];
          uint32_t j = (uint32_t)row * (uint32_t)N + (uint32_t)col;
          v = drop_keep(k0, k1, j) ? fmaxf(v * 1.25f, 0.f) : 0.f;
          uint16_t h = f2bf(v);
          Chi[o] = h;
          Clo[o] = f2bf(v - bf2f(h));
        }
      }
    }
  }
}

// ------------------------- layer-1 aggregation (f16 gather, MLP-8) ----------------
// out[t] = dinv[t] * sum_{s in N(t) U {t}} xs16[s]
__global__ __launch_bounds__(256) void k_agg_x(const uint16_t* __restrict__ xs,
                                               const float* __restrict__ dinv,
                                               const int* __restrict__ row_start,
                                               const int* __restrict__ csr_src,
                                               uint32_t* __restrict__ outh,
                                               uint32_t* __restrict__ outl, int n) {
  const int F = 128;
  int wid = (int)((blockIdx.x * 256 + threadIdx.x) >> 6);
  if (wid >= n) return;
  int lane = threadIdx.x & 63;
  int t = wid;
  float2 a[8];
  {
    __half2 h = ((const __half2*)(xs + (size_t)t * F))[lane];
    a[0] = __half22float2(h);
  }
#pragma unroll
  for (int q = 1; q < 8; ++q) a[q] = make_float2(0.f, 0.f);
  int e0 = row_start[t], e1 = row_start[t + 1];
  int e = e0;
  for (; e + 8 <= e1; e += 8) {
#pragma unroll
    for (int q = 0; q < 8; ++q) {
      int s = csr_src[e + q];
      __half2 h = ((const __half2*)(xs + (size_t)s * F))[lane];
      float2 v = __half22float2(h);
      a[q].x += v.x;
      a[q].y += v.y;
    }
  }
  for (; e < e1; ++e) {
    int s = csr_src[e];
    __half2 h = ((const __half2*)(xs + (size_t)s * F))[lane];
    float2 v = __half22float2(h);
    a[0].x += v.x; a[0].y += v.y;
  }
  float dt = dinv[t];
  float rx = (((a[0].x + a[1].x) + (a[2].x + a[3].x)) + ((a[4].x + a[5].x) + (a[6].x + a[7].x))) * dt;
  float ry = (((a[0].y + a[1].y) + (a[2].y + a[3].y)) + ((a[4].y + a[5].y) + (a[6].y + a[7].y))) * dt;
  uint16_t hx = f2bf(rx), hy = f2bf(ry);
  uint16_t lx = f2bf(rx - bf2f(hx)), ly = f2bf(ry - bf2f(hy));
  outh[(size_t)t * 64 + lane] = (uint32_t)hx | ((uint32_t)hy << 16);
  outl[(size_t)t * 64 + lane] = (uint32_t)lx | ((uint32_t)ly << 16);
}

// ------------------------- layer-2 aggregation + bias + drop + relu (f16 gather) --
__global__ __launch_bounds__(256) void k_agg_w(const uint16_t* __restrict__ hws,
                                               const float* __restrict__ dinv,
                                               const float* __restrict__ bias,
                                               const int* __restrict__ row_start,
                                               const int* __restrict__ csr_src,
                                               uint32_t* __restrict__ outh,
                                               uint32_t* __restrict__ outl,
                                               uint32_t k0, uint32_t k1, int n) {
  const int F = 128;
  int wid = (int)((blockIdx.x * 256 + threadIdx.x) >> 6);
  if (wid >= n) return;
  int lane = threadIdx.x & 63;
  int t = wid;
  float2 a[8];
  {
    __half2 h = ((const __half2*)(hws + (size_t)t * F))[lane];
    a[0] = __half22float2(h);
  }
#pragma unroll
  for (int q = 1; q < 8; ++q) a[q] = make_float2(0.f, 0.f);
  int e0 = row_start[t], e1 = row_start[t + 1];
  int e = e0;
  for (; e + 8 <= e1; e += 8) {
#pragma unroll
    for (int q = 0; q < 8; ++q) {
      int s = csr_src[e + q];
      __half2 h = ((const __half2*)(hws + (size_t)s * F))[lane];
      float2 v = __half22float2(h);
      a[q].x += v.x;
      a[q].y += v.y;
    }
  }
  for (; e < e1; ++e) {
    int s = csr_src[e];
    __half2 h = ((const __half2*)(hws + (size_t)s * F))[lane];
    float2 v = __half22float2(h);
    a[0].x += v.x; a[0].y += v.y;
  }
  float d = dinv[t];
  float sx = ((a[0].x + a[1].x) + (a[2].x + a[3].x)) + ((a[4].x + a[5].x) + (a[6].x + a[7].x));
  float sy = ((a[0].y + a[1].y) + (a[2].y + a[3].y)) + ((a[4].y + a[5].y) + (a[6].y + a[7].y));
  float vx = sx * d + bias[lane * 2];
  float vy = sy * d + bias[lane * 2 + 1];
  uint32_t j = (uint32_t)t * 128u + (uint32_t)lane * 2u;
  vx = drop_keep(k0, k1, j)     ? fmaxf(vx * 1.25f, 0.f) : 0.f;
  vy = drop_keep(k0, k1, j + 1) ? fmaxf(vy * 1.25f, 0.f) : 0.f;
  uint16_t hx = f2bf(vx), hy = f2bf(vy);
  uint16_t lx = f2bf(vx - bf2f(hx)), ly = f2bf(vy - bf2f(hy));
  outh[(size_t)t * 64 + lane] = (uint32_t)hx | ((uint32_t)hy << 16);
  outl[(size_t)t * 64 + lane] = (uint32_t)lx | ((uint32_t)ly << 16);
}

// ------------------------- launch -------------------------
static inline size_t ws_align(size_t x) { return (x + 255) & ~(size_t)255; }

extern "C" void kernel_launch(void* const* d_in, const int* in_sizes, int n_in,
                              void* d_out, int out_size, void* d_ws, size_t ws_size,
                              hipStream_t stream) {
  const float* x  = (const float*)d_in[0];
  const float* W1 = (const float*)d_in[1];
  const float* b1 = (const float*)d_in[2];
  const float* W2 = (const float*)d_in[3];
  const float* b2 = (const float*)d_in[4];
  const float* W3 = (const float*)d_in[5];
  const float* b3 = (const float*)d_in[6];
  const int*   ei = (const int*)d_in[7];

  const int IN = 128, H2 = 256, HID = 128, OD = 64;
  const int n = in_sizes[0] / IN;   // 50000
  const int E = in_sizes[7] / 2;    // 800000
  const int* esrc = ei;
  const int* etgt = ei + E;
  const int nb = (n + 255) / 256;
  const int Mb64 = (n + 63) / 64;   // 782
  const int Mpad = Mb64 * 64;       // 50048

  char* w = (char*)d_ws;
  size_t off = 0;
  auto alloc = [&](size_t bytes) { void* p = w + off; off += ws_align(bytes); return p; };
  float*    dinv      = (float*)alloc((size_t)n * 4);
  int*      cnt       = (int*)alloc((size_t)n * 4);
  int*      cursor    = (int*)alloc((size_t)n * 4);
  int*      row_start = (int*)alloc(((size_t)n + 1) * 4);
  int*      bsum      = (int*)alloc(256 * 4);
  int*      bbase     = (int*)alloc(256 * 4);
  int*      csr_src   = (int*)alloc((size_t)E * 4);
  uint16_t* xs16      = (uint16_t*)alloc((size_t)n * IN * 2);
  uint16_t* A1h       = (uint16_t*)alloc((size_t)Mpad * IN * 2);   // ag / h2 (aliased)
  uint16_t* A1l       = (uint16_t*)alloc((size_t)Mpad * IN * 2);
  uint16_t* h1h       = (uint16_t*)alloc((size_t)Mpad * H2 * 2);
  uint16_t* h1l       = (uint16_t*)alloc((size_t)Mpad * H2 * 2);
  uint16_t* hw2_16    = (uint16_t*)alloc((size_t)n * HID * 2);
  uint16_t* Wt1h      = (uint16_t*)alloc((size_t)H2 * IN * 2);
  uint16_t* Wt1l      = (uint16_t*)alloc((size_t)H2 * IN * 2);
  uint16_t* Wt2h      = (uint16_t*)alloc((size_t)HID * H2 * 2);
  uint16_t* Wt2l      = (uint16_t*)alloc((size_t)HID * H2 * 2);
  uint16_t* Wt3h      = (uint16_t*)alloc((size_t)OD * IN * 2);
  uint16_t* Wt3l      = (uint16_t*)alloc((size_t)OD * IN * 2);
  (void)ws_size;

  hipFuncSetAttribute((const void*)&k_mfma<0>,
                      hipFuncAttributeMaxDynamicSharedMemorySize, 65536);
  hipFuncSetAttribute((const void*)&k_mfma<1>,
                      hipFuncAttributeMaxDynamicSharedMemorySize, 65536);
  hipFuncSetAttribute((const void*)&k_mfma<2>,
                      hipFuncAttributeMaxDynamicSharedMemorySize, 65536);

  uint32_t dk1_0, dk1_1, dk2_0, dk2_1;
  threefry2x32(0u, 42u, 0u, 0u, dk1_0, dk1_1);
  threefry2x32(0u, 42u, 0u, 1u, dk2_0, dk2_1);

  int padrows = Mpad - n;  // 48
  hipMemsetAsync(A1h + (size_t)n * IN, 0, (size_t)padrows * IN * 2, stream);
  hipMemsetAsync(A1l + (size_t)n * IN, 0, (size_t)padrows * IN * 2, stream);
  hipMemsetAsync(h1h + (size_t)n * H2, 0, (size_t)padrows * H2 * 2, stream);
  hipMemsetAsync(h1l + (size_t)n * H2, 0, (size_t)padrows * H2 * 2, stream);
  hipMemsetAsync(cnt, 0, (size_t)n * 4, stream);
  hipMemsetAsync(cursor, 0, (size_t)n * 4, stream);

  k_cvtW<<<(H2 * IN + 255) / 256, 256, 0, stream>>>(W1, Wt1h, Wt1l, IN, H2);
  k_cvtW<<<(HID * H2 + 255) / 256, 256, 0, stream>>>(W2, Wt2h, Wt2l, H2, HID);
  k_cvtW<<<(OD * IN + 255) / 256, 256, 0, stream>>>(W3, Wt3h, Wt3l, IN, OD);

  k_hist<<<(E + 255) / 256, 256, 0, stream>>>(etgt, cnt, E);
  k_scan1<<<nb, 256, 0, stream>>>(cnt, row_start, bsum, dinv, n);
  k_scan2<<<1, 256, 0, stream>>>(bsum, bbase, row_start, nb, n);
  k_scan3<<<nb, 256, 0, stream>>>(row_start, bbase, n);
  k_scatter<<<(E + 255) / 256, 256, 0, stream>>>(esrc, etgt, row_start, cursor, csr_src, E);

  // layer 1
  int total2 = n * IN / 2;
  k_scale16<<<(total2 + 255) / 256, 256, 0, stream>>>(x, dinv, xs16, total2);
  k_agg_x<<<(n + 3) / 4, 256, 0, stream>>>(xs16, dinv, row_start, csr_src,
                                           (uint32_t*)A1h, (uint32_t*)A1l, n);
  {
    dim3 g(Mb64, H2 / 64);
    k_mfma<2><<<g, 256, 65536, stream>>>(A1h, A1l, Wt1h, Wt1l, b1, nullptr,
                                         h1h, h1l, n, H2, IN, dk1_0, dk1_1);
  }

  // layer 2
  {
    dim3 g(Mb64, HID / 64);
    k_mfma<0><<<g, 256, 65536, stream>>>(h1h, h1l, Wt2h, Wt2l, dinv, nullptr,
                                         hw2_16, nullptr, n, HID, H2, 0u, 0u);
  }
  k_agg_w<<<(n + 3) / 4, 256, 0, stream>>>(hw2_16, dinv, b2, row_start, csr_src,
                                           (uint32_t*)A1h, (uint32_t*)A1l, dk2_0, dk2_1, n);

  // layer 3
  {
    dim3 g(Mb64, OD / 64);
    k_mfma<1><<<g, 256, 65536, stream>>>(A1h, A1l, Wt3h, Wt3l, b3, (float*)d_out,
                                         nullptr, nullptr, n, OD, IN, 0u, 0u);
  }
}